// Round 1
// baseline (935.525 us; speedup 1.0000x reference)
//
#include <hip/hip_runtime.h>
#include <hip/hip_bf16.h>

// Problem constants (fixed by reference):
// N=400000, H=256, C=128, A=32, G=512, NG=1024, BN_EPS=1e-5
#define NNODES 400000
#define BM 64            // nodes per block in K1 (400000/64 = 6250 exact)

typedef __attribute__((ext_vector_type(8))) short  short8;   // 8 x bf16 (4 VGPRs)
typedef __attribute__((ext_vector_type(4))) float  floatx4;  // 4 x f32 acc

typedef unsigned short u16;
typedef unsigned int   u32;

// fp32 -> bf16 round-to-nearest-even (inputs are finite gaussians; no NaN path)
__device__ __forceinline__ short f2bf(float f) {
    u32 u = __builtin_bit_cast(u32, f);
    u += 0x7fffu + ((u >> 16) & 1u);
    return (short)(u >> 16);
}

// async 16B/lane global->LDS copy; dst must be wave-uniform base (HW adds lane*16)
__device__ __forceinline__ void async16(const void* g, void* l) {
    __builtin_amdgcn_global_load_lds(
        (const __attribute__((address_space(1))) u32*)g,
        (__attribute__((address_space(3))) u32*)l, 16, 0, 0);
}

// ---------------------------------------------------------------------------
// K0: build combined bf16 weight matrix Bp in MFMA/staging-friendly order.
// Logical B[k][col], k in [0,512), col in [0,256):
//   col <  128 : Wg[k][col]              (gate head, X = [init | final])
//   col >= 128 : k>=256 ? Wt[k-256][col-128] : 0   (transform head, final only)
// Layout: Bp[kc][quad][col][j], k = kc*32 + quad*8 + j  (16B contiguous per
// (kc,quad,col) -> ds_read_b128 B-fragments, 1KB-contiguous chunks for staging)
// ---------------------------------------------------------------------------
__global__ __launch_bounds__(256) void k0_build(
    const float* __restrict__ Wg, const float* __restrict__ Wt,
    u16* __restrict__ Bp)
{
    int base = (blockIdx.x * 256 + threadIdx.x) * 4;
    #pragma unroll
    for (int e = 0; e < 4; e++) {
        int idx  = base + e;                  // 131072 total
        int j    = idx & 7;
        int col  = (idx >> 3) & 255;
        int quad = (idx >> 11) & 3;
        int kc   = idx >> 13;
        int k    = kc * 32 + quad * 8 + j;
        float v;
        if (col < 128)       v = Wg[k * 128 + col];
        else if (k >= 256)   v = Wt[(k - 256) * 128 + (col - 128)];
        else                 v = 0.0f;
        Bp[idx] = (u16)f2bf(v);
    }
}

// ---------------------------------------------------------------------------
// K1: node GEMM (bf16 MFMA) + sigmoid-gate + sorted segment-sum via atomics.
// Block: 256 threads = 4 waves; wave w owns node rows [w*16, w*16+16).
// Output cols 0..127 = gate pre-act, 128..255 = transform pre-act.
// ---------------------------------------------------------------------------
__global__ __launch_bounds__(256) void k1_gemm(
    const float* __restrict__ initS, const float* __restrict__ finS,
    const int* __restrict__ gids, const u16* __restrict__ Bp,
    const float* __restrict__ bg, const float* __restrict__ bt,
    float* __restrict__ readout)
{
    __shared__ __align__(16) u16  Bl[4][256][8];   // 16 KB B tile [quad][col][j]
    __shared__ float nodew[BM][128];               // 32 KB nodewise values
    __shared__ int   gidL[BM];

    const int tid  = threadIdx.x;
    const int w    = tid >> 6;        // wave 0..3
    const int lane = tid & 63;
    const int quad = lane >> 4;       // 0..3
    const int l15  = lane & 15;       // 0..15
    const int nodeBase = blockIdx.x * BM;

    if (tid < BM) gidL[tid] = gids[nodeBase + tid];

    floatx4 acc[16];
    #pragma unroll
    for (int i = 0; i < 16; i++) acc[i] = (floatx4){0.f, 0.f, 0.f, 0.f};

    const int rowNode = nodeBase + w * 16 + l15;   // A row this lane feeds
    const float* initRow = initS + (size_t)rowNode * 256;
    const float* finRow  = finS  + (size_t)rowNode * 256;
    const int chunk = w * 4;   // wave stages 4 x 1KB chunks of the 16KB tile

    for (int kc = 0; kc < 16; kc++) {
        // stage B tile: 16 async 1KB wave-copies (4 per wave)
        #pragma unroll
        for (int i = 0; i < 4; i++) {
            const u16* gsrc = Bp + (size_t)kc * 8192 + (chunk + i) * 512 + lane * 8;
            u16* ldst = &Bl[0][0][0] + (chunk + i) * 512;  // wave-uniform base
            async16(gsrc, ldst);
        }
        // A fragment: 8 consecutive fp32 -> bf16x8 (k = kc*32 + quad*8 + j)
        const float* ar = (kc < 8) ? (initRow + kc * 32 + quad * 8)
                                   : (finRow + (kc - 8) * 32 + quad * 8);
        float4 a0 = *reinterpret_cast<const float4*>(ar);
        float4 a1 = *reinterpret_cast<const float4*>(ar + 4);
        short8 af;
        af[0] = f2bf(a0.x); af[1] = f2bf(a0.y); af[2] = f2bf(a0.z); af[3] = f2bf(a0.w);
        af[4] = f2bf(a1.x); af[5] = f2bf(a1.y); af[6] = f2bf(a1.z); af[7] = f2bf(a1.w);

        __syncthreads();   // staging drained (sync waits vmcnt) before ds_read
        #pragma unroll
        for (int ct = 0; ct < 16; ct++) {
            short8 bf = *reinterpret_cast<const short8*>(&Bl[quad][ct * 16 + l15][0]);
            acc[ct] = __builtin_amdgcn_mfma_f32_16x16x32_bf16(af, bf, acc[ct], 0, 0, 0);
        }
        __syncthreads();   // tile consumed; next iter may overwrite
    }

    // Epilogue: nodewise[n][c] = sigmoid(gate+bg) * (t+bt).
    // C/D layout: col = lane&15 (within 16-tile), row = quad*4 + reg.
    // Gate tile ct and transform tile ct+8 share the same lane -> in-lane fuse.
    #pragma unroll
    for (int ct = 0; ct < 8; ct++) {
        const int c = ct * 16 + l15;
        const float bgv = bg[c];
        const float btv = bt[c];
        #pragma unroll
        for (int i = 0; i < 4; i++) {
            const int r = quad * 4 + i;
            float g = acc[ct][i] + bgv;
            float t = acc[ct + 8][i] + btv;
            float s = 1.0f / (1.0f + __expf(-g));
            nodew[w * 16 + r][c] = s * t;
        }
    }
    __syncthreads();

    // Sorted segment-sum: thread = (col, row-half); flush on gid change.
    {
        const int c  = tid & 127;
        const int r0 = (tid >> 7) * 32;
        float s = 0.f;
        int cur = gidL[r0];
        for (int r = r0; r < r0 + 32; r++) {
            int g = gidL[r];
            if (g != cur) {
                atomicAdd(&readout[cur * 128 + c], s);
                s = 0.f; cur = g;
            }
            s += nodew[r][c];
        }
        atomicAdd(&readout[cur * 128 + c], s);
    }
}

// ---------------------------------------------------------------------------
// K2: BatchNorm column stats over the 1024-row batch (biased variance),
// folded into scale/shift: y = x*scale[c] + shift[c].
// ---------------------------------------------------------------------------
__global__ __launch_bounds__(256) void k2_stats(
    const float* __restrict__ readout, const float* __restrict__ aux,
    const float* __restrict__ gamma, const float* __restrict__ beta,
    float* __restrict__ scale, float* __restrict__ shift)
{
    const int col = blockIdx.x;     // 0..159
    const int tid = threadIdx.x;
    float s = 0.f, q = 0.f;
    for (int g = tid; g < 1024; g += 256) {
        float v = (col < 128) ? readout[g * 128 + col] : aux[g * 32 + (col - 128)];
        s += v; q += v * v;
    }
    #pragma unroll
    for (int off = 32; off > 0; off >>= 1) {
        s += __shfl_down(s, off);
        q += __shfl_down(q, off);
    }
    __shared__ float ps[4], pq[4];
    if ((tid & 63) == 0) { ps[tid >> 6] = s; pq[tid >> 6] = q; }
    __syncthreads();
    if (tid == 0) {
        float S = ps[0] + ps[1] + ps[2] + ps[3];
        float Q = pq[0] + pq[1] + pq[2] + pq[3];
        float mean = S * (1.0f / 1024.0f);
        float var  = Q * (1.0f / 1024.0f) - mean * mean;
        float rstd = rsqrtf(var + 1e-5f);
        float sc   = gamma[col] * rstd;
        scale[col] = sc;
        shift[col] = beta[col] - mean * sc;
    }
}

// ---------------------------------------------------------------------------
// K3a: hidden = relu(norm @ W1 + b1), BN fold applied inside the k-loop so the
// activations are RAW global rows (wave-uniform addresses -> scalar loads).
// Block: 4 graph rows; thread: 2 hidden cols, 4-row register accumulation.
// ---------------------------------------------------------------------------
__global__ __launch_bounds__(256) void k3a_hidden(
    const float* __restrict__ readout, const float* __restrict__ aux,
    const float* __restrict__ scale, const float* __restrict__ shift,
    const float* __restrict__ W1, const float* __restrict__ b1,
    float* __restrict__ hidden)
{
    const int g0  = blockIdx.x * 4;   // 256 blocks
    const int tid = threadIdx.x;
    const float* r0 = readout + (size_t)g0 * 128;
    const float* a0 = aux     + (size_t)g0 * 32;

    #pragma unroll
    for (int jj = 0; jj < 2; jj++) {
        const int j = tid + jj * 256;
        float acc0 = 0.f, acc1 = 0.f, acc2 = 0.f, acc3 = 0.f, accS = 0.f;
        for (int k = 0; k < 128; k++) {
            float wv = W1[k * 512 + j];
            accS += shift[k] * wv;
            float wsv = scale[k] * wv;
            acc0 += r0[k]       * wsv;
            acc1 += r0[128 + k] * wsv;
            acc2 += r0[256 + k] * wsv;
            acc3 += r0[384 + k] * wsv;
        }
        for (int k = 0; k < 32; k++) {
            float wv = W1[(128 + k) * 512 + j];
            accS += shift[128 + k] * wv;
            float wsv = scale[128 + k] * wv;
            acc0 += a0[k]      * wsv;
            acc1 += a0[32 + k] * wsv;
            acc2 += a0[64 + k] * wsv;
            acc3 += a0[96 + k] * wsv;
        }
        float bb = b1[j] + accS;
        hidden[(size_t)(g0 + 0) * 512 + j] = fmaxf(acc0 + bb, 0.f);
        hidden[(size_t)(g0 + 1) * 512 + j] = fmaxf(acc1 + bb, 0.f);
        hidden[(size_t)(g0 + 2) * 512 + j] = fmaxf(acc2 + bb, 0.f);
        hidden[(size_t)(g0 + 3) * 512 + j] = fmaxf(acc3 + bb, 0.f);
    }
}

// ---------------------------------------------------------------------------
// K3b: logits = hidden @ W2 + b2. Same uniform-broadcast trick on hidden rows.
// Block: 4 graph rows; thread: 1 of 128 cols x 2 rows (tid>>7 selects row pair).
// ---------------------------------------------------------------------------
__global__ __launch_bounds__(256) void k3b_logits(
    const float* __restrict__ hidden, const float* __restrict__ W2,
    const float* __restrict__ b2, float* __restrict__ out)
{
    const int g0  = blockIdx.x * 4;   // 256 blocks
    const int tid = threadIdx.x;
    const int j   = tid & 127;
    const int rh  = tid >> 7;         // rows rh*2, rh*2+1
    const float* h0 = hidden + (size_t)(g0 + rh * 2) * 512;
    float acc0 = 0.f, acc1 = 0.f;
    for (int k = 0; k < 512; k++) {
        float wv = W2[k * 128 + j];
        acc0 += h0[k]       * wv;
        acc1 += h0[512 + k] * wv;
    }
    float bb = b2[j];
    out[(size_t)(g0 + rh * 2 + 0) * 128 + j] = acc0 + bb;
    out[(size_t)(g0 + rh * 2 + 1) * 128 + j] = acc1 + bb;
}

// ---------------------------------------------------------------------------
extern "C" void kernel_launch(void* const* d_in, const int* in_sizes, int n_in,
                              void* d_out, int out_size, void* d_ws, size_t ws_size,
                              hipStream_t stream)
{
    const float* initS = (const float*)d_in[0];   // [400000,256]
    const float* finS  = (const float*)d_in[1];   // [400000,256]
    const float* aux   = (const float*)d_in[2];   // [1024,32]
    const int*   gid   = (const int*)d_in[3];     // [400000] sorted
    // d_in[4] = num_graphs scalar (1024), unused
    const float* Wg    = (const float*)d_in[5];   // [512,128]
    const float* bg    = (const float*)d_in[6];   // [128]
    const float* Wt    = (const float*)d_in[7];   // [256,128]
    const float* bt    = (const float*)d_in[8];   // [128]
    const float* gamma = (const float*)d_in[9];   // [160]
    const float* beta  = (const float*)d_in[10];  // [160]
    const float* W1    = (const float*)d_in[11];  // [160,512]
    const float* b1    = (const float*)d_in[12];  // [512]
    const float* W2    = (const float*)d_in[13];  // [512,128]
    const float* b2    = (const float*)d_in[14];  // [128]
    float* out = (float*)d_out;                   // [1024,128]

    char* ws = (char*)d_ws;
    u16*   Bp      = (u16*)(ws + 0);              // 256 KB packed bf16 weights
    float* readout = (float*)(ws + 262144);       // 512 KB  [1024,128]
    float* scale   = (float*)(ws + 786432);       // 640 B
    float* shift   = (float*)(ws + 787456);       // 640 B
    float* hidden  = (float*)(ws + 1048576);      // 2 MB    [1024,512]

    k0_build  <<<128, 256, 0, stream>>>(Wg, Wt, Bp);
    hipMemsetAsync(readout, 0, 1024 * 128 * sizeof(float), stream);
    k1_gemm   <<<NNODES / BM, 256, 0, stream>>>(initS, finS, gid, Bp, bg, bt, readout);
    k2_stats  <<<160, 256, 0, stream>>>(readout, aux, gamma, beta, scale, shift);
    k3a_hidden<<<256, 256, 0, stream>>>(readout, aux, scale, shift, W1, b1, hidden);
    k3b_logits<<<256, 256, 0, stream>>>(hidden, W2, b2, out);
}

// Round 2
// 925.327 us; speedup vs baseline: 1.0110x; 1.0110x over previous
//
#include <hip/hip_runtime.h>
#include <hip/hip_bf16.h>

// Problem constants (fixed by reference):
// N=400000, H=256, C=128, A=32, G=512, NG=1024, BN_EPS=1e-5
#define NNODES 400000
#define BM 64            // nodes per block in K1 (400000/64 = 6250 exact)

typedef __attribute__((ext_vector_type(8))) short  short8;   // 8 x bf16 (4 VGPRs)
typedef __attribute__((ext_vector_type(4))) float  floatx4;  // 4 x f32 acc

typedef unsigned short u16;
typedef unsigned int   u32;

// fp32 -> bf16 round-to-nearest-even (inputs are finite gaussians; no NaN path)
__device__ __forceinline__ short f2bf(float f) {
    u32 u = __builtin_bit_cast(u32, f);
    u += 0x7fffu + ((u >> 16) & 1u);
    return (short)(u >> 16);
}

// async 16B/lane global->LDS copy; dst is wave-uniform base (HW adds lane*16)
__device__ __forceinline__ void async16(const void* g, void* l) {
    __builtin_amdgcn_global_load_lds(
        (const __attribute__((address_space(1))) u32*)g,
        (__attribute__((address_space(3))) u32*)l, 16, 0, 0);
}

// ---------------------------------------------------------------------------
// K0: build packed bf16 weights, zero-free two-section layout.
//   Gate section (64K u16):  idx = kc*4096 + quad*1024 + col*8 + j
//                            value = Wg[kc*32+quad*8+j][col],  kc 0..15
//   T section    (32K u16):  idx = 65536 + kct*4096 + quad*1024 + col*8 + j
//                            value = Wt[kct*32+quad*8+j][col], kct 0..7
// 16B contiguous per (tile,quad,col) -> ds_read_b128 B-frags; 1KB-contiguous
// chunks for wave-uniform global_load_lds staging.
// ---------------------------------------------------------------------------
__global__ __launch_bounds__(256) void k0_build(
    const float* __restrict__ Wg, const float* __restrict__ Wt,
    u16* __restrict__ Bp)
{
    int base = (blockIdx.x * 256 + threadIdx.x) * 4;   // 96 blocks -> 98304
    #pragma unroll
    for (int e = 0; e < 4; e++) {
        int idx   = base + e;
        int local = idx & 4095;
        int quad  = local >> 10;
        int col   = (local >> 3) & 127;
        int j     = local & 7;
        float v;
        if (idx < 65536) {
            int kc = idx >> 12;
            v = Wg[(kc * 32 + quad * 8 + j) * 128 + col];
        } else {
            int kct = (idx - 65536) >> 12;
            v = Wt[(kct * 32 + quad * 8 + j) * 128 + col];
        }
        Bp[idx] = (u16)f2bf(v);
    }
}

// ---------------------------------------------------------------------------
// K1: node GEMM (bf16 MFMA) + sigmoid-gate + register segment-sum.
// Block: 256 threads = 4 waves; wave w owns node rows [w*16, w*16+16).
// Phase 1 (kc 0..7):  A = init rows, gate tiles only      (8 MFMA/iter)
// Phase 2 (kc 8..15): A = fin rows, gate + t tiles        (16 MFMA/iter)
// Double-buffered B staging, one barrier per iteration, A prefetched 1 iter
// ahead. Epilogue: sigmoid(g)*t in-lane, cross-quad shfl_xor reduction,
// 1 atomic per column per wave on the (~96%) gid-uniform fast path.
// ---------------------------------------------------------------------------
__global__ __launch_bounds__(256, 4) void k1_gemm(
    const float* __restrict__ initS, const float* __restrict__ finS,
    const int* __restrict__ gids, const u16* __restrict__ Bp,
    const float* __restrict__ bg, const float* __restrict__ bt,
    float* __restrict__ readout)
{
    __shared__ __align__(16) u16 Bl[2][8192];   // 2 x 16 KB B tiles
    __shared__ int gidL[BM];

    const int tid  = threadIdx.x;
    const int w    = tid >> 6;        // wave 0..3
    const int lane = tid & 63;
    const int quad = lane >> 4;       // 0..3
    const int l15  = lane & 15;       // 0..15
    const int nodeBase = blockIdx.x * BM;

    if (tid < BM) gidL[tid] = gids[nodeBase + tid];

    floatx4 accg[8], acct[8];
    #pragma unroll
    for (int i = 0; i < 8; i++) {
        accg[i] = (floatx4){0.f, 0.f, 0.f, 0.f};
        acct[i] = (floatx4){0.f, 0.f, 0.f, 0.f};
    }

    const int rowNode = nodeBase + w * 16 + l15;   // A row this lane feeds
    const float* initRow = initS + (size_t)rowNode * 256;
    const float* finRow  = finS  + (size_t)rowNode * 256;

    // --- stage helper (inlined twice): gate tile = chunks 0..7, t = 8..15 ---
    auto stage = [&](int kc, u16* lbuf) {
        if (kc < 8) {                       // 8 KB: gate only, 2 chunks/wave
            #pragma unroll
            for (int i = 0; i < 2; i++) {
                int c = w * 2 + i;
                async16(Bp + (size_t)kc * 4096 + c * 512 + lane * 8, lbuf + c * 512);
            }
        } else {                            // 16 KB: gate + t, 4 chunks/wave
            #pragma unroll
            for (int i = 0; i < 4; i++) {
                int c = w * 4 + i;
                const u16* src = (c < 8)
                    ? (Bp + (size_t)kc * 4096 + c * 512)
                    : (Bp + 65536 + (size_t)(kc - 8) * 4096 + (c - 8) * 512);
                async16(src + lane * 8, lbuf + c * 512);
            }
        }
    };

    // prologue: stage tile 0, load A(0)
    stage(0, Bl[0]);
    const float* ar = initRow + quad * 8;
    float4 a0 = *reinterpret_cast<const float4*>(ar);
    float4 a1 = *reinterpret_cast<const float4*>(ar + 4);

    for (int kc = 0; kc < 16; kc++) {
        const u16* cur = Bl[kc & 1];
        __syncthreads();   // publishes B(kc) staging + A(kc) prefetch (vmcnt drain)

        float4 a0n, a1n;
        if (kc < 15) {
            stage(kc + 1, Bl[(kc + 1) & 1]);           // in flight across MFMAs
            const float* arn = ((kc + 1) < 8)
                ? (initRow + (kc + 1) * 32 + quad * 8)
                : (finRow + (kc + 1 - 8) * 32 + quad * 8);
            a0n = *reinterpret_cast<const float4*>(arn);
            a1n = *reinterpret_cast<const float4*>(arn + 4);
        }

        short8 af;
        af[0] = f2bf(a0.x); af[1] = f2bf(a0.y); af[2] = f2bf(a0.z); af[3] = f2bf(a0.w);
        af[4] = f2bf(a1.x); af[5] = f2bf(a1.y); af[6] = f2bf(a1.z); af[7] = f2bf(a1.w);

        #pragma unroll
        for (int ct = 0; ct < 8; ct++) {
            short8 bf = *reinterpret_cast<const short8*>(
                cur + quad * 1024 + (ct * 16 + l15) * 8);
            accg[ct] = __builtin_amdgcn_mfma_f32_16x16x32_bf16(af, bf, accg[ct], 0, 0, 0);
        }
        if (kc >= 8) {
            #pragma unroll
            for (int ct = 0; ct < 8; ct++) {
                short8 bf = *reinterpret_cast<const short8*>(
                    cur + 4096 + quad * 1024 + (ct * 16 + l15) * 8);
                acct[ct] = __builtin_amdgcn_mfma_f32_16x16x32_bf16(af, bf, acct[ct], 0, 0, 0);
            }
        }
        a0 = a0n; a1 = a1n;
    }

    // ---- epilogue: fuse + segment-sum from registers ----
    // C/D layout: col = ct*16 + l15, row (within wave tile) = quad*4 + reg.
    const int rbase = w * 16;
    const int gFirst = gidL[rbase];
    const int gLast  = gidL[rbase + 15];

    if (gFirst == gLast) {
        // fast path: whole 16-row wave tile in one graph
        #pragma unroll
        for (int ct = 0; ct < 8; ct++) {
            const float bgv = bg[ct * 16 + l15];
            const float btv = bt[ct * 16 + l15];
            float s = 0.f;
            #pragma unroll
            for (int i = 0; i < 4; i++) {
                float g = accg[ct][i] + bgv;
                float t = acct[ct][i] + btv;
                s += t / (1.0f + __expf(-g));
            }
            s += __shfl_xor(s, 16);   // sum across quads (rows)
            s += __shfl_xor(s, 32);
            if ((ct >> 1) == quad)    // 1 atomic per column per wave
                atomicAdd(&readout[gFirst * 128 + ct * 16 + l15], s);
        }
    } else {
        // slow path (~4% of waves): per-lane sorted-run flush over its 4 rows
        float s[8];
        #pragma unroll
        for (int ct = 0; ct < 8; ct++) s[ct] = 0.f;
        int curg = gidL[rbase + quad * 4];
        #pragma unroll
        for (int i = 0; i < 4; i++) {
            int g = gidL[rbase + quad * 4 + i];
            if (g != curg) {
                #pragma unroll
                for (int ct = 0; ct < 8; ct++) {
                    atomicAdd(&readout[curg * 128 + ct * 16 + l15], s[ct]);
                    s[ct] = 0.f;
                }
                curg = g;
            }
            #pragma unroll
            for (int ct = 0; ct < 8; ct++) {
                float gg = accg[ct][i] + bg[ct * 16 + l15];
                float tt = acct[ct][i] + bt[ct * 16 + l15];
                s[ct] += tt / (1.0f + __expf(-gg));
            }
        }
        #pragma unroll
        for (int ct = 0; ct < 8; ct++)
            atomicAdd(&readout[curg * 128 + ct * 16 + l15], s[ct]);
    }
}

// ---------------------------------------------------------------------------
// K2: BatchNorm column stats over the 1024-row batch (biased variance),
// folded into scale/shift: y = x*scale[c] + shift[c].
// ---------------------------------------------------------------------------
__global__ __launch_bounds__(256) void k2_stats(
    const float* __restrict__ readout, const float* __restrict__ aux,
    const float* __restrict__ gamma, const float* __restrict__ beta,
    float* __restrict__ scale, float* __restrict__ shift)
{
    const int col = blockIdx.x;     // 0..159
    const int tid = threadIdx.x;
    float s = 0.f, q = 0.f;
    for (int g = tid; g < 1024; g += 256) {
        float v = (col < 128) ? readout[g * 128 + col] : aux[g * 32 + (col - 128)];
        s += v; q += v * v;
    }
    #pragma unroll
    for (int off = 32; off > 0; off >>= 1) {
        s += __shfl_down(s, off);
        q += __shfl_down(q, off);
    }
    __shared__ float ps[4], pq[4];
    if ((tid & 63) == 0) { ps[tid >> 6] = s; pq[tid >> 6] = q; }
    __syncthreads();
    if (tid == 0) {
        float S = ps[0] + ps[1] + ps[2] + ps[3];
        float Q = pq[0] + pq[1] + pq[2] + pq[3];
        float mean = S * (1.0f / 1024.0f);
        float var  = Q * (1.0f / 1024.0f) - mean * mean;
        float rstd = rsqrtf(var + 1e-5f);
        float sc   = gamma[col] * rstd;
        scale[col] = sc;
        shift[col] = beta[col] - mean * sc;
    }
}

// ---------------------------------------------------------------------------
// K3a: hidden = relu(norm @ W1 + b1), BN fold applied inside the k-loop so the
// activations are RAW global rows (wave-uniform addresses -> scalar loads).
// ---------------------------------------------------------------------------
__global__ __launch_bounds__(256) void k3a_hidden(
    const float* __restrict__ readout, const float* __restrict__ aux,
    const float* __restrict__ scale, const float* __restrict__ shift,
    const float* __restrict__ W1, const float* __restrict__ b1,
    float* __restrict__ hidden)
{
    const int g0  = blockIdx.x * 4;   // 256 blocks
    const int tid = threadIdx.x;
    const float* r0 = readout + (size_t)g0 * 128;
    const float* a0 = aux     + (size_t)g0 * 32;

    #pragma unroll
    for (int jj = 0; jj < 2; jj++) {
        const int j = tid + jj * 256;
        float acc0 = 0.f, acc1 = 0.f, acc2 = 0.f, acc3 = 0.f, accS = 0.f;
        for (int k = 0; k < 128; k++) {
            float wv = W1[k * 512 + j];
            accS += shift[k] * wv;
            float wsv = scale[k] * wv;
            acc0 += r0[k]       * wsv;
            acc1 += r0[128 + k] * wsv;
            acc2 += r0[256 + k] * wsv;
            acc3 += r0[384 + k] * wsv;
        }
        for (int k = 0; k < 32; k++) {
            float wv = W1[(128 + k) * 512 + j];
            accS += shift[128 + k] * wv;
            float wsv = scale[128 + k] * wv;
            acc0 += a0[k]      * wsv;
            acc1 += a0[32 + k] * wsv;
            acc2 += a0[64 + k] * wsv;
            acc3 += a0[96 + k] * wsv;
        }
        float bb = b1[j] + accS;
        hidden[(size_t)(g0 + 0) * 512 + j] = fmaxf(acc0 + bb, 0.f);
        hidden[(size_t)(g0 + 1) * 512 + j] = fmaxf(acc1 + bb, 0.f);
        hidden[(size_t)(g0 + 2) * 512 + j] = fmaxf(acc2 + bb, 0.f);
        hidden[(size_t)(g0 + 3) * 512 + j] = fmaxf(acc3 + bb, 0.f);
    }
}

// ---------------------------------------------------------------------------
// K3b: logits = hidden @ W2 + b2. Same uniform-broadcast trick on hidden rows.
// ---------------------------------------------------------------------------
__global__ __launch_bounds__(256) void k3b_logits(
    const float* __restrict__ hidden, const float* __restrict__ W2,
    const float* __restrict__ b2, float* __restrict__ out)
{
    const int g0  = blockIdx.x * 4;   // 256 blocks
    const int tid = threadIdx.x;
    const int j   = tid & 127;
    const int rh  = tid >> 7;         // rows rh*2, rh*2+1
    const float* h0 = hidden + (size_t)(g0 + rh * 2) * 512;
    float acc0 = 0.f, acc1 = 0.f;
    for (int k = 0; k < 512; k++) {
        float wv = W2[k * 128 + j];
        acc0 += h0[k]       * wv;
        acc1 += h0[512 + k] * wv;
    }
    float bb = b2[j];
    out[(size_t)(g0 + rh * 2 + 0) * 128 + j] = acc0 + bb;
    out[(size_t)(g0 + rh * 2 + 1) * 128 + j] = acc1 + bb;
}

// ---------------------------------------------------------------------------
extern "C" void kernel_launch(void* const* d_in, const int* in_sizes, int n_in,
                              void* d_out, int out_size, void* d_ws, size_t ws_size,
                              hipStream_t stream)
{
    const float* initS = (const float*)d_in[0];   // [400000,256]
    const float* finS  = (const float*)d_in[1];   // [400000,256]
    const float* aux   = (const float*)d_in[2];   // [1024,32]
    const int*   gid   = (const int*)d_in[3];     // [400000] sorted
    // d_in[4] = num_graphs scalar (1024), unused
    const float* Wg    = (const float*)d_in[5];   // [512,128]
    const float* bg    = (const float*)d_in[6];   // [128]
    const float* Wt    = (const float*)d_in[7];   // [256,128]
    const float* bt    = (const float*)d_in[8];   // [128]
    const float* gamma = (const float*)d_in[9];   // [160]
    const float* beta  = (const float*)d_in[10];  // [160]
    const float* W1    = (const float*)d_in[11];  // [160,512]
    const float* b1    = (const float*)d_in[12];  // [512]
    const float* W2    = (const float*)d_in[13];  // [512,128]
    const float* b2    = (const float*)d_in[14];  // [128]
    float* out = (float*)d_out;                   // [1024,128]

    char* ws = (char*)d_ws;
    u16*   Bp      = (u16*)(ws + 0);              // 192 KB packed bf16 weights
    float* readout = (float*)(ws + 262144);       // 512 KB  [1024,128]
    float* scale   = (float*)(ws + 786432);       // 640 B
    float* shift   = (float*)(ws + 787456);       // 640 B
    float* hidden  = (float*)(ws + 1048576);      // 2 MB    [1024,512]

    k0_build  <<<96, 256, 0, stream>>>(Wg, Wt, Bp);
    hipMemsetAsync(readout, 0, 1024 * 128 * sizeof(float), stream);
    k1_gemm   <<<NNODES / BM, 256, 0, stream>>>(initS, finS, gid, Bp, bg, bt, readout);
    k2_stats  <<<160, 256, 0, stream>>>(readout, aux, gamma, beta, scale, shift);
    k3a_hidden<<<256, 256, 0, stream>>>(readout, aux, scale, shift, W1, b1, hidden);
    k3b_logits<<<256, 256, 0, stream>>>(hidden, W2, b2, out);
}